// Round 1
// baseline (135.247 us; speedup 1.0000x reference)
//
#include <hip/hip_runtime.h>

typedef _Float16 f16x8 __attribute__((ext_vector_type(8)));
typedef float    f32x4 __attribute__((ext_vector_type(4)));

#define N_ROWS 8192
#define DIM 64
#define EPS 1e-8f
#define LOG2E 1.4426950408889634f
#define SHIFT 64.0f                      // exp terms scaled by 2^64
#define SHIFT_LN 44.361419555836499802f  // 64 * ln(2)
#define TILE 128                         // symmetric block-pair tile (i and j)
#define NTJ (TILE / 16)                  // 8 j-subtiles per block
#define NB (N_ROWS / TILE)               // 64 tiles per side
#define TB (NB * (NB + 1) / 2)           // 2080 lower-triangle block pairs

// ws: top[8192] | bot[8192] | sq[8192] (f32) | xh[8192*64] | xl[8192*64] (f16)

// fused: zero top/bot/out + f16 split + row norms. one wave per row.
__global__ void snn_prep(const float* __restrict__ x, _Float16* __restrict__ xh,
                         _Float16* __restrict__ xl, float* __restrict__ sq,
                         float* __restrict__ top, float* __restrict__ bot,
                         float* __restrict__ out) {
    const int gt = blockIdx.x * 256 + threadIdx.x;
    if (gt < N_ROWS) { top[gt] = 0.0f; bot[gt] = 0.0f; }
    if (gt == 0) out[0] = 0.0f;
    const int row = gt >> 6, lane = threadIdx.x & 63;
    float v = x[row * DIM + lane];
    _Float16 h = (_Float16)v;
    _Float16 l = (_Float16)(v - (float)h);
    xh[row * DIM + lane] = h;
    xl[row * DIM + lane] = l;
    float s = v * v;
    #pragma unroll
    for (int off = 32; off > 0; off >>= 1) s += __shfl_xor(s, off, 64);
    if (lane == 0) sq[row] = s;
}

// Symmetric (triangular) pass: d(i,j)=d(j,i) and the class mask is symmetric,
// so each lower-triangle 128x128 tile accumulates into BOTH row-i (ts/bs) and
// col-j (LDS s_jt/s_jb) halves. Halves MFMA + transcendental work vs full grid.
// block = 4 waves, each wave owns 32 i-rows (mt=2); j-chunk = 128 (8 subtiles).
// launch_bounds(256,2): proven no-spill regime from prior session (VGPR<=256).
__global__ __launch_bounds__(256, 2) void snn_mfma(
    const _Float16* __restrict__ xh, const _Float16* __restrict__ xl,
    const float* __restrict__ sq, const int* __restrict__ y,
    const float* __restrict__ w,
    float* __restrict__ top, float* __restrict__ bot)
{
    __shared__ float s_sqj[TILE];
    __shared__ int   s_yj[TILE];
    __shared__ float s_jt[TILE];   // column-side top accumulator (off-diag only)
    __shared__ float s_jb[TILE];   // column-side bot accumulator

    // linear bid -> lower-triangle (bi, bj), bi >= bj
    const int bid = blockIdx.x;
    int r = (int)((sqrtf(8.0f * (float)bid + 1.0f) - 1.0f) * 0.5f);
    while ((r + 1) * (r + 2) / 2 <= bid) ++r;   // fp guard
    while (r * (r + 1) / 2 > bid) --r;
    const int bi = r, bj = bid - r * (r + 1) / 2;
    const bool diag = (bi == bj);
    const int I0 = bi * TILE, J0 = bj * TILE;

    const int tid = threadIdx.x, wv = tid >> 6, lane = tid & 63;
    const int mrow = lane & 15, kq = lane >> 4;

    if (tid < TILE) {
        s_sqj[tid] = sq[J0 + tid];
        s_yj[tid]  = y[J0 + tid];
        s_jt[tid]  = 0.0f;
        s_jb[tid]  = 0.0f;
    }
    __syncthreads();

    const int iw = I0 + wv * 32;   // this wave's first i-row

    // A fragments resident for the block lifetime (32 VGPRs)
    f16x8 ah[2][2], al[2][2];
    #pragma unroll
    for (int mt = 0; mt < 2; mt++)
        #pragma unroll
        for (int kc = 0; kc < 2; kc++) {
            int a = (iw + mt * 16 + mrow) * DIM + kc * 32 + kq * 8;
            ah[mt][kc] = *(const f16x8*)(xh + a);
            al[mt][kc] = *(const f16x8*)(xl + a);
        }

    // per-slot row metadata: i = iw + mt*16 + kq*4 + rr
    float sqi[2][4]; int yi[2][4];
    #pragma unroll
    for (int mt = 0; mt < 2; mt++)
        #pragma unroll
        for (int rr = 0; rr < 4; rr++) {
            int i = iw + mt * 16 + kq * 4 + rr;
            sqi[mt][rr] = sq[i];
            yi[mt][rr]  = y[i];
        }

    float ts[2][4], bs[2][4];
    #pragma unroll
    for (int mt = 0; mt < 2; mt++)
        #pragma unroll
        for (int rr = 0; rr < 4; rr++) { ts[mt][rr] = 0.0f; bs[mt][rr] = 0.0f; }

    const float c1 = -w[0] * LOG2E;

#define LOAD_B_AND_MFMA(NT_)                                                     \
    const int jbase = J0 + (NT_) * 16;                                           \
    const int boff = (jbase + mrow) * DIM + kq * 8;                              \
    f16x8 bh0 = *(const f16x8*)(xh + boff);                                      \
    f16x8 bh1 = *(const f16x8*)(xh + boff + 32);                                 \
    f16x8 bl0 = *(const f16x8*)(xl + boff);                                      \
    f16x8 bl1 = *(const f16x8*)(xl + boff + 32);                                 \
    const float sqj = s_sqj[(NT_) * 16 + mrow];                                  \
    const int   yj  = s_yj[(NT_) * 16 + mrow];                                   \
    f32x4 acc[2];                                                                \
    acc[0] = (f32x4){0.f, 0.f, 0.f, 0.f};                                        \
    acc[1] = (f32x4){0.f, 0.f, 0.f, 0.f};                                        \
    _Pragma("unroll")                                                            \
    for (int mt = 0; mt < 2; mt++)                                               \
        acc[mt] = __builtin_amdgcn_mfma_f32_16x16x32_f16(ah[mt][0], bh0, acc[mt], 0, 0, 0); \
    _Pragma("unroll")                                                            \
    for (int mt = 0; mt < 2; mt++)                                               \
        acc[mt] = __builtin_amdgcn_mfma_f32_16x16x32_f16(ah[mt][1], bh1, acc[mt], 0, 0, 0); \
    _Pragma("unroll")                                                            \
    for (int mt = 0; mt < 2; mt++)                                               \
        acc[mt] = __builtin_amdgcn_mfma_f32_16x16x32_f16(ah[mt][0], bl0, acc[mt], 0, 0, 0); \
    _Pragma("unroll")                                                            \
    for (int mt = 0; mt < 2; mt++)                                               \
        acc[mt] = __builtin_amdgcn_mfma_f32_16x16x32_f16(ah[mt][1], bl1, acc[mt], 0, 0, 0); \
    _Pragma("unroll")                                                            \
    for (int mt = 0; mt < 2; mt++)                                               \
        acc[mt] = __builtin_amdgcn_mfma_f32_16x16x32_f16(al[mt][0], bh0, acc[mt], 0, 0, 0); \
    _Pragma("unroll")                                                            \
    for (int mt = 0; mt < 2; mt++)                                               \
        acc[mt] = __builtin_amdgcn_mfma_f32_16x16x32_f16(al[mt][1], bh1, acc[mt], 0, 0, 0);

    if (!diag) {
        // off-diagonal: i != j always; accumulate both row-i and col-j sides
        for (int nt = 0; nt < NTJ; nt++) {
            LOAD_B_AND_MFMA(nt)
            float jt = 0.0f, jbv = 0.0f;
            #pragma unroll
            for (int mt = 0; mt < 2; mt++)
                #pragma unroll
                for (int rr = 0; rr < 4; rr++) {
                    float d2 = fmaf(-2.0f, acc[mt][rr], sqi[mt][rr] + sqj);
                    d2 = fmaxf(d2, 0.0f);
                    float dist = __builtin_amdgcn_sqrtf(d2);
                    float e2 = exp2f(fmaf(c1, dist, SHIFT));
                    float e2t = (yj == yi[mt][rr]) ? e2 : 0.0f;
                    ts[mt][rr] += e2t;
                    bs[mt][rr] += e2;
                    jt  += e2t;
                    jbv += e2;
                }
            // reduce col-side over the 4 kq groups (rows of the fragment)
            jt  += __shfl_xor(jt, 16, 64);  jt  += __shfl_xor(jt, 32, 64);
            jbv += __shfl_xor(jbv, 16, 64); jbv += __shfl_xor(jbv, 32, 64);
            if (kq == 0) {                          // 16 lanes, distinct j
                atomicAdd(&s_jt[nt * 16 + mrow], jt);
                atomicAdd(&s_jb[nt * 16 + mrow], jbv);
            }
        }
    } else {
        // diagonal tile: covers both directions already; guard i==j, no j-side
        for (int nt = 0; nt < NTJ; nt++) {
            LOAD_B_AND_MFMA(nt)
            const int j = jbase + mrow;
            #pragma unroll
            for (int mt = 0; mt < 2; mt++)
                #pragma unroll
                for (int rr = 0; rr < 4; rr++) {
                    int i = iw + mt * 16 + kq * 4 + rr;
                    float d2 = fmaf(-2.0f, acc[mt][rr], sqi[mt][rr] + sqj);
                    d2 = fmaxf(d2, 0.0f);
                    float dist = __builtin_amdgcn_sqrtf(d2);
                    float e2 = exp2f(fmaf(c1, dist, SHIFT));
                    bool offd = (i != j);
                    bool same = offd && (yj == yi[mt][rr]);
                    bs[mt][rr] += offd ? e2 : 0.0f;
                    ts[mt][rr] += same ? e2 : 0.0f;
                }
        }
    }
#undef LOAD_B_AND_MFMA

    // row-side: reduce across the 16 mrow lanes sharing each row, one atomic/row
    #pragma unroll
    for (int mt = 0; mt < 2; mt++)
        #pragma unroll
        for (int rr = 0; rr < 4; rr++) {
            float tv = ts[mt][rr], bv = bs[mt][rr];
            #pragma unroll
            for (int off = 1; off < 16; off <<= 1) {
                tv += __shfl_xor(tv, off, 64);
                bv += __shfl_xor(bv, off, 64);
            }
            if (mrow == 0) {
                int i = iw + mt * 16 + kq * 4 + rr;
                atomicAdd(&top[i], tv);
                atomicAdd(&bot[i], bv);
            }
        }

    // col-side drain: one atomic per column per block
    if (!diag) {
        __syncthreads();
        if (tid < TILE) {
            atomicAdd(&top[J0 + tid], s_jt[tid]);
            atomicAdd(&bot[J0 + tid], s_jb[tid]);
        }
    }
}

__global__ __launch_bounds__(256) void snn_final(
    const float* __restrict__ top, const float* __restrict__ bot,
    float* __restrict__ out)
{
    const int i = blockIdx.x * 256 + threadIdx.x;
    float t = top[i];                    // top * 2^64, normal fp32
    float b = bot[i] * 0x1p-64f + EPS;   // bot tiny; +eps dominates
    float acc = (logf(t) - SHIFT_LN) - logf(b);
    #pragma unroll
    for (int off = 32; off > 0; off >>= 1) acc += __shfl_xor(acc, off, 64);
    __shared__ float red[4];
    if ((threadIdx.x & 63) == 0) red[threadIdx.x >> 6] = acc;
    __syncthreads();
    if (threadIdx.x == 0) {
        float s = red[0] + red[1] + red[2] + red[3];
        atomicAdd(out, -s / (float)N_ROWS);
    }
}

extern "C" void kernel_launch(void* const* d_in, const int* in_sizes, int n_in,
                              void* d_out, int out_size, void* d_ws, size_t ws_size,
                              hipStream_t stream) {
    const float* x = (const float*)d_in[0];
    const int*   y = (const int*)d_in[1];
    const float* w = (const float*)d_in[2];
    float* out = (float*)d_out;

    float* ws  = (float*)d_ws;
    float* top = ws;
    float* bot = ws + N_ROWS;
    float* sq  = ws + 2 * N_ROWS;
    _Float16* xh = (_Float16*)(ws + 3 * N_ROWS);
    _Float16* xl = xh + (size_t)N_ROWS * DIM;

    snn_prep<<<N_ROWS / 4, 256, 0, stream>>>(x, xh, xl, sq, top, bot, out);
    snn_mfma<<<TB, 256, 0, stream>>>(xh, xl, sq, y, w, top, bot);
    snn_final<<<N_ROWS / 256, 256, 0, stream>>>(top, bot, out);
}

// Round 2
// 117.254 us; speedup vs baseline: 1.1535x; 1.1535x over previous
//
#include <hip/hip_runtime.h>

typedef _Float16 f16x8 __attribute__((ext_vector_type(8)));
typedef float    f32x4 __attribute__((ext_vector_type(4)));

#define N_ROWS 8192
#define DIM 64
#define EPS 1e-8f
#define LOG2E 1.4426950408889634f
#define SHIFT 64.0f                      // exp terms scaled by 2^64
#define SHIFT_LN 44.361419555836499802f  // 64 * ln(2)
#define TILE_I 256                       // i-tile (4 waves x 64 rows, mt=4)
#define TILE_J 128                       // j-chunk
#define NTJ (TILE_J / 16)                // 8 j-subtiles per block
#define NBI (N_ROWS / TILE_I)            // 32 i-tiles
#define TB (NBI * (NBI + 1))             // 1056 blocks: per bi, bj=0..2bi+1

// ws: top[8192] | bot[8192] | sq[8192] (f32) | xh[8192*64] | xl[8192*64] (f16)

// fused: zero top/bot/out + f16 split + row norms. one wave per row.
__global__ void snn_prep(const float* __restrict__ x, _Float16* __restrict__ xh,
                         _Float16* __restrict__ xl, float* __restrict__ sq,
                         float* __restrict__ top, float* __restrict__ bot,
                         float* __restrict__ out) {
    const int gt = blockIdx.x * 256 + threadIdx.x;
    if (gt < N_ROWS) { top[gt] = 0.0f; bot[gt] = 0.0f; }
    if (gt == 0) out[0] = 0.0f;
    const int row = gt >> 6, lane = threadIdx.x & 63;
    float v = x[row * DIM + lane];
    _Float16 h = (_Float16)v;
    _Float16 l = (_Float16)(v - (float)h);
    xh[row * DIM + lane] = h;
    xl[row * DIM + lane] = l;
    float s = v * v;
    #pragma unroll
    for (int off = 32; off > 0; off >>= 1) s += __shfl_xor(s, off, 64);
    if (lane == 0) sq[row] = s;
}

// Symmetric triangular pass with ASYMMETRIC 256x128 tiles.
// Per i-tile bi (256 rows): blocks bj = 0..2bi+1.
//   bj <  2bi  : j-range strictly below i-range -> both-sides accumulation
//                (row-i via regs, col-j via per-wave LDS slices), no i==j test.
//   bj >= 2bi  : half of the 256x256 diagonal square -> one-sided with i!=j
//                guard (the two half-blocks visit both orders of each pair).
// Every unordered pair counted exactly once; 0.516x the pair-visits of the
// full grid while keeping the proven wave shape: 64 i-rows/wave (mt=4),
// 24 MFMAs + 16 epilogue elems per B-load (round-1 regression was mt=2's
// halved amortization + halved MFMA ILP + LDS-atomic contention).
__global__ __launch_bounds__(256, 2) void snn_mfma(
    const _Float16* __restrict__ xh, const _Float16* __restrict__ xl,
    const float* __restrict__ sq, const int* __restrict__ y,
    const float* __restrict__ w,
    float* __restrict__ top, float* __restrict__ bot)
{
    __shared__ float s_sqj[TILE_J];
    __shared__ int   s_yj[TILE_J];
    __shared__ float s_jt[4][TILE_J];  // per-wave col-side top (no atomics)
    __shared__ float s_jb[4][TILE_J];  // per-wave col-side bot

    // bid -> (bi, bj): cumulative blocks before bi is bi*(bi+1)
    const int bid = blockIdx.x;
    int bi = (int)((sqrtf(4.0f * (float)bid + 1.0f) - 1.0f) * 0.5f);
    while ((bi + 1) * (bi + 2) <= bid) ++bi;   // fp guards
    while (bi * (bi + 1) > bid) --bi;
    const int bj = bid - bi * (bi + 1);
    const bool diag = (bj >= 2 * bi);
    const int I0 = bi * TILE_I, J0 = bj * TILE_J;

    const int tid = threadIdx.x, wv = tid >> 6, lane = tid & 63;
    const int mrow = lane & 15, kq = lane >> 4;

    if (tid < TILE_J) {
        s_sqj[tid] = sq[J0 + tid];
        s_yj[tid]  = y[J0 + tid];
    }
    __syncthreads();

    const int iw = I0 + wv * 64;   // this wave's first i-row

    // A fragments resident for the block lifetime (64 VGPRs)
    f16x8 ah[4][2], al[4][2];
    #pragma unroll
    for (int mt = 0; mt < 4; mt++)
        #pragma unroll
        for (int kc = 0; kc < 2; kc++) {
            int a = (iw + mt * 16 + mrow) * DIM + kc * 32 + kq * 8;
            ah[mt][kc] = *(const f16x8*)(xh + a);
            al[mt][kc] = *(const f16x8*)(xl + a);
        }

    // per-slot row metadata: i = iw + mt*16 + kq*4 + rr ; labels packed 4/VGPR
    float sqi[4][4]; int ypack[4];
    #pragma unroll
    for (int mt = 0; mt < 4; mt++) {
        int yp = 0;
        #pragma unroll
        for (int rr = 0; rr < 4; rr++) {
            int i = iw + mt * 16 + kq * 4 + rr;
            sqi[mt][rr] = sq[i];
            yp |= (y[i] & 255) << (8 * rr);
        }
        ypack[mt] = yp;
    }

    float ts[4][4], bs[4][4];
    #pragma unroll
    for (int mt = 0; mt < 4; mt++)
        #pragma unroll
        for (int rr = 0; rr < 4; rr++) { ts[mt][rr] = 0.0f; bs[mt][rr] = 0.0f; }

    const float c1 = -w[0] * LOG2E;

#define LOAD_B_AND_MFMA(NT_)                                                     \
    const int jbase = J0 + (NT_) * 16;                                           \
    const int boff = (jbase + mrow) * DIM + kq * 8;                              \
    f16x8 bh0 = *(const f16x8*)(xh + boff);                                      \
    f16x8 bh1 = *(const f16x8*)(xh + boff + 32);                                 \
    f16x8 bl0 = *(const f16x8*)(xl + boff);                                      \
    f16x8 bl1 = *(const f16x8*)(xl + boff + 32);                                 \
    const float sqj = s_sqj[(NT_) * 16 + mrow];                                  \
    const int   yj  = s_yj[(NT_) * 16 + mrow];                                   \
    f32x4 acc[4];                                                                \
    _Pragma("unroll")                                                            \
    for (int mt = 0; mt < 4; mt++) acc[mt] = (f32x4){0.f, 0.f, 0.f, 0.f};        \
    _Pragma("unroll")                                                            \
    for (int mt = 0; mt < 4; mt++)                                               \
        acc[mt] = __builtin_amdgcn_mfma_f32_16x16x32_f16(ah[mt][0], bh0, acc[mt], 0, 0, 0); \
    _Pragma("unroll")                                                            \
    for (int mt = 0; mt < 4; mt++)                                               \
        acc[mt] = __builtin_amdgcn_mfma_f32_16x16x32_f16(ah[mt][1], bh1, acc[mt], 0, 0, 0); \
    _Pragma("unroll")                                                            \
    for (int mt = 0; mt < 4; mt++)                                               \
        acc[mt] = __builtin_amdgcn_mfma_f32_16x16x32_f16(ah[mt][0], bl0, acc[mt], 0, 0, 0); \
    _Pragma("unroll")                                                            \
    for (int mt = 0; mt < 4; mt++)                                               \
        acc[mt] = __builtin_amdgcn_mfma_f32_16x16x32_f16(ah[mt][1], bl1, acc[mt], 0, 0, 0); \
    _Pragma("unroll")                                                            \
    for (int mt = 0; mt < 4; mt++)                                               \
        acc[mt] = __builtin_amdgcn_mfma_f32_16x16x32_f16(al[mt][0], bh0, acc[mt], 0, 0, 0); \
    _Pragma("unroll")                                                            \
    for (int mt = 0; mt < 4; mt++)                                               \
        acc[mt] = __builtin_amdgcn_mfma_f32_16x16x32_f16(al[mt][1], bh1, acc[mt], 0, 0, 0);

    if (!diag) {
        // strictly below diagonal: i != j guaranteed; accumulate both sides
        for (int nt = 0; nt < NTJ; nt++) {
            LOAD_B_AND_MFMA(nt)
            float jt = 0.0f, jb = 0.0f;
            #pragma unroll
            for (int mt = 0; mt < 4; mt++)
                #pragma unroll
                for (int rr = 0; rr < 4; rr++) {
                    float d2 = fmaf(-2.0f, acc[mt][rr], sqi[mt][rr] + sqj);
                    d2 = fmaxf(d2, 0.0f);
                    float dist = __builtin_amdgcn_sqrtf(d2);
                    float e2 = exp2f(fmaf(c1, dist, SHIFT));
                    float e2t = (yj == ((ypack[mt] >> (8 * rr)) & 255)) ? e2 : 0.0f;
                    ts[mt][rr] += e2t;
                    bs[mt][rr] += e2;
                    jt += e2t;
                    jb += e2;
                }
            // col-side: reduce over the 4 kq groups; each (wv,col) written once
            jt += __shfl_xor(jt, 16, 64); jt += __shfl_xor(jt, 32, 64);
            jb += __shfl_xor(jb, 16, 64); jb += __shfl_xor(jb, 32, 64);
            if (kq == 0) {
                s_jt[wv][nt * 16 + mrow] = jt;
                s_jb[wv][nt * 16 + mrow] = jb;
            }
        }
    } else {
        // diagonal square half: one-sided, guard i==j
        for (int nt = 0; nt < NTJ; nt++) {
            LOAD_B_AND_MFMA(nt)
            const int j = jbase + mrow;
            #pragma unroll
            for (int mt = 0; mt < 4; mt++)
                #pragma unroll
                for (int rr = 0; rr < 4; rr++) {
                    int i = iw + mt * 16 + kq * 4 + rr;
                    float d2 = fmaf(-2.0f, acc[mt][rr], sqi[mt][rr] + sqj);
                    d2 = fmaxf(d2, 0.0f);
                    float dist = __builtin_amdgcn_sqrtf(d2);
                    float e2 = exp2f(fmaf(c1, dist, SHIFT));
                    bool offd = (i != j);
                    bool same = offd && (yj == ((ypack[mt] >> (8 * rr)) & 255));
                    bs[mt][rr] += offd ? e2 : 0.0f;
                    ts[mt][rr] += same ? e2 : 0.0f;
                }
        }
    }
#undef LOAD_B_AND_MFMA

    // row-side: reduce across the 16 mrow lanes sharing each row, one atomic/row
    #pragma unroll
    for (int mt = 0; mt < 4; mt++)
        #pragma unroll
        for (int rr = 0; rr < 4; rr++) {
            float tv = ts[mt][rr], bv = bs[mt][rr];
            #pragma unroll
            for (int off = 1; off < 16; off <<= 1) {
                tv += __shfl_xor(tv, off, 64);
                bv += __shfl_xor(bv, off, 64);
            }
            if (mrow == 0) {
                int i = iw + mt * 16 + kq * 4 + rr;
                atomicAdd(&top[i], tv);
                atomicAdd(&bot[i], bv);
            }
        }

    // col-side drain: sum the 4 per-wave slices, one atomic per column
    if (!diag) {
        __syncthreads();
        if (tid < TILE_J) {
            float t = s_jt[0][tid] + s_jt[1][tid] + s_jt[2][tid] + s_jt[3][tid];
            float b = s_jb[0][tid] + s_jb[1][tid] + s_jb[2][tid] + s_jb[3][tid];
            atomicAdd(&top[J0 + tid], t);
            atomicAdd(&bot[J0 + tid], b);
        }
    }
}

__global__ __launch_bounds__(256) void snn_final(
    const float* __restrict__ top, const float* __restrict__ bot,
    float* __restrict__ out)
{
    const int i = blockIdx.x * 256 + threadIdx.x;
    float t = top[i];                    // top * 2^64, normal fp32
    float b = bot[i] * 0x1p-64f + EPS;   // bot tiny; +eps dominates
    float acc = (logf(t) - SHIFT_LN) - logf(b);
    #pragma unroll
    for (int off = 32; off > 0; off >>= 1) acc += __shfl_xor(acc, off, 64);
    __shared__ float red[4];
    if ((threadIdx.x & 63) == 0) red[threadIdx.x >> 6] = acc;
    __syncthreads();
    if (threadIdx.x == 0) {
        float s = red[0] + red[1] + red[2] + red[3];
        atomicAdd(out, -s / (float)N_ROWS);
    }
}

extern "C" void kernel_launch(void* const* d_in, const int* in_sizes, int n_in,
                              void* d_out, int out_size, void* d_ws, size_t ws_size,
                              hipStream_t stream) {
    const float* x = (const float*)d_in[0];
    const int*   y = (const int*)d_in[1];
    const float* w = (const float*)d_in[2];
    float* out = (float*)d_out;

    float* ws  = (float*)d_ws;
    float* top = ws;
    float* bot = ws + N_ROWS;
    float* sq  = ws + 2 * N_ROWS;
    _Float16* xh = (_Float16*)(ws + 3 * N_ROWS);
    _Float16* xl = xh + (size_t)N_ROWS * DIM;

    snn_prep<<<N_ROWS / 4, 256, 0, stream>>>(x, xh, xl, sq, top, bot, out);
    snn_mfma<<<TB, 256, 0, stream>>>(xh, xl, sq, y, w, top, bot);
    snn_final<<<N_ROWS / 256, 256, 0, stream>>>(top, bot, out);
}